// Round 1
// baseline (20.505 us; speedup 1.0000x reference)
//
#include <hip/hip_runtime.h>

// CNN2: reference collapses because Y = W @ ones(30,T) is rank-1 (every column
// == rowsum(W)). Per-lag trace normalization cancels the lag-dependent overlap
// count, so S_mean is lag-independent:
//   Sm = r r^T / ||r||^2,  Sv = 0  (exactly, up to fp noise ~1e-17)
//   Gm = 0.5*(Sm+1), Gv = 0.5 (constant channel)
// Remaining work: tiny 2-layer CNN + maxpools + 16->2 linear. One block.

#define NN 30

__global__ __launch_bounds__(1024) void cnn2_fused(
    const float* __restrict__ W,
    const float* __restrict__ c1w, const float* __restrict__ c1b,
    const float* __restrict__ c2w, const float* __restrict__ c2b,
    const float* __restrict__ ow,  const float* __restrict__ ob,
    float* __restrict__ out)
{
    __shared__ float r[NN];
    __shared__ float s_ssq;
    __shared__ float gm[NN][NN];      // Gm channel
    __shared__ float c1[8][29][29];   // conv1 output, post-leaky
    __shared__ float p1[8][3][3];     // pool1
    __shared__ float c2o[16][4][4];   // conv2 output, post-leaky
    __shared__ float hvec[16];        // pool2 / flattened features

    const int tid = threadIdx.x;

    // r[i] = rowsum of W
    if (tid < NN) {
        float s = 0.f;
        for (int j = 0; j < NN; ++j) s += W[tid * NN + j];
        r[tid] = s;
    }
    __syncthreads();

    if (tid == 0) {
        float s = 0.f;
        for (int i = 0; i < NN; ++i) s += r[i] * r[i];
        s_ssq = s;
    }
    __syncthreads();

    // Gm[i][j] = 0.5*(r_i r_j / ||r||^2 + 1)
    if (tid < NN * NN) {
        int i = tid / NN, j = tid % NN;
        gm[i][j] = 0.5f * (r[i] * r[j] / s_ssq + 1.0f);
    }
    __syncthreads();

    // conv1 (8,2,4,4), pad 1: in (2,30,30) -> out (8,29,29); channel 1 is
    // constant 0.5 (zero in the padding ring), then LeakyReLU(0.2).
    for (int o = tid; o < 8 * 29 * 29; o += (int)blockDim.x) {
        int oc  = o / (29 * 29);
        int rem = o % (29 * 29);
        int oy  = rem / 29, ox = rem % 29;
        float acc = c1b[oc];
        #pragma unroll
        for (int ky = 0; ky < 4; ++ky) {
            int iy = oy + ky - 1;
            if (iy < 0 || iy >= NN) continue;
            #pragma unroll
            for (int kx = 0; kx < 4; ++kx) {
                int ix = ox + kx - 1;
                if (ix < 0 || ix >= NN) continue;
                float w0 = c1w[((oc * 2 + 0) * 4 + ky) * 4 + kx];
                float w1 = c1w[((oc * 2 + 1) * 4 + ky) * 4 + kx];
                acc += gm[iy][ix] * w0 + 0.5f * w1;
            }
        }
        c1[oc][oy][ox] = acc >= 0.f ? acc : 0.2f * acc;
    }
    __syncthreads();

    // maxpool 8x8 stride 8 VALID: (8,29,29) -> (8,3,3)
    if (tid < 8 * 3 * 3) {
        int oc = tid / 9, py = (tid % 9) / 3, px = tid % 3;
        float m = -INFINITY;
        for (int dy = 0; dy < 8; ++dy)
            for (int dx = 0; dx < 8; ++dx) {
                float v = c1[oc][py * 8 + dy][px * 8 + dx];
                m = v > m ? v : m;
            }
        p1[oc][py][px] = m;
    }
    __syncthreads();

    // conv2 (16,8,2,2), pad 1: (8,3,3) -> (16,4,4), LeakyReLU(0.2)
    if (tid < 16 * 4 * 4) {
        int oc = tid / 16, rem = tid % 16;
        int oy = rem / 4, ox = rem % 4;
        float acc = c2b[oc];
        for (int ic = 0; ic < 8; ++ic) {
            #pragma unroll
            for (int ky = 0; ky < 2; ++ky) {
                int iy = oy + ky - 1;
                if (iy < 0 || iy >= 3) continue;
                #pragma unroll
                for (int kx = 0; kx < 2; ++kx) {
                    int ix = ox + kx - 1;
                    if (ix < 0 || ix >= 3) continue;
                    acc += p1[ic][iy][ix] * c2w[((oc * 8 + ic) * 2 + ky) * 2 + kx];
                }
            }
        }
        c2o[oc][oy][ox] = acc >= 0.f ? acc : 0.2f * acc;
    }
    __syncthreads();

    // maxpool 4x4: (16,4,4) -> (16,)
    if (tid < 16) {
        float m = -INFINITY;
        for (int dy = 0; dy < 4; ++dy)
            for (int dx = 0; dx < 4; ++dx) {
                float v = c2o[tid][dy][dx];
                m = v > m ? v : m;
            }
        hvec[tid] = m;
    }
    __syncthreads();

    // final linear: out[k] = sum_c h[c]*out_w[k,c] + out_b[k]
    if (tid < 2) {
        float acc = ob[tid];
        for (int c = 0; c < 16; ++c) acc += hvec[c] * ow[tid * 16 + c];
        out[tid] = acc;
    }
}

extern "C" void kernel_launch(void* const* d_in, const int* in_sizes, int n_in,
                              void* d_out, int out_size, void* d_ws, size_t ws_size,
                              hipStream_t stream) {
    // d_in order (setup_inputs dict): 0=x(unused), 1=W, 2=conv1_w, 3=conv1_b,
    // 4=conv2_w, 5=conv2_b, 6=out_w, 7=out_b, 8=col(unused — cancels in
    // trace normalization)
    const float* W   = (const float*)d_in[1];
    const float* c1w = (const float*)d_in[2];
    const float* c1b = (const float*)d_in[3];
    const float* c2w = (const float*)d_in[4];
    const float* c2b = (const float*)d_in[5];
    const float* ow  = (const float*)d_in[6];
    const float* ob  = (const float*)d_in[7];
    float* out = (float*)d_out;

    cnn2_fused<<<1, 1024, 0, stream>>>(W, c1w, c1b, c2w, c2b, ow, ob, out);
}

// Round 2
// 16.904 us; speedup vs baseline: 1.2130x; 1.2130x over previous
//
#include <hip/hip_runtime.h>

// CNN2: reference collapses because Y = W @ ones(30,T) is rank-1 (every column
// == rowsum(W)). Per-lag trace normalization cancels the lag-dependent overlap
// count, so S_mean is lag-independent:
//   Sm = r r^T / ||r||^2,  Sv = 0  (fp noise ~1e-17)
//   Gm = 0.5*(Sm+1), Gv = 0.5 (constant channel)
// Remaining: tiny 2-layer CNN + maxpools + 16->2 linear. One block, one CU.
// R1: prefetch ALL globals in one parallel burst before the first barrier
// (overlap every HBM-miss latency); shuffle-reduce ssq; W rowsum from LDS.

#define NN 30

__global__ __launch_bounds__(1024) void cnn2_fused(
    const float* __restrict__ W,
    const float* __restrict__ c1w, const float* __restrict__ c1b,
    const float* __restrict__ c2w, const float* __restrict__ c2b,
    const float* __restrict__ ow,  const float* __restrict__ ob,
    float* __restrict__ out)
{
    __shared__ float w[NN * NN];      // staged W
    __shared__ float s_c1w[256];
    __shared__ float s_c1b[8];
    __shared__ float s_c2w[512];
    __shared__ float s_c2b[16];
    __shared__ float s_ow[32];
    __shared__ float s_ob[2];
    __shared__ float r[NN];
    __shared__ float s_inv;           // 1/||r||^2
    __shared__ float gm[NN][NN];      // Gm channel
    __shared__ float c1[8][29][29];   // conv1 output, post-leaky
    __shared__ float p1[8][3][3];     // pool1
    __shared__ float c2o[16][4][4];   // conv2 output, post-leaky
    __shared__ float hvec[16];        // pool2 / flattened features

    const int tid = threadIdx.x;

    // ---- Phase A: issue every global load before the first barrier ----
    // (independent loads; vmcnt pipelines them — one HBM round-trip total)
    if (tid < 900) w[tid]     = W[tid];
    if (tid < 256) s_c1w[tid] = c1w[tid];
    if (tid < 8)   s_c1b[tid] = c1b[tid];
    if (tid < 512) s_c2w[tid] = c2w[tid];
    if (tid < 16)  s_c2b[tid] = c2b[tid];
    if (tid < 32)  s_ow[tid]  = ow[tid];
    if (tid < 2)   s_ob[tid]  = ob[tid];
    __syncthreads();

    // ---- r[i] = rowsum of W (from LDS) ----
    if (tid < NN) {
        float s = 0.f;
        #pragma unroll
        for (int j = 0; j < NN; ++j) s += w[tid * NN + j];
        r[tid] = s;
    }
    __syncthreads();

    // ---- ssq via wave shuffle reduce (first wave only) ----
    if (tid < 64) {
        float v = (tid < NN) ? r[tid] : 0.f;
        v *= v;
        #pragma unroll
        for (int off = 32; off > 0; off >>= 1) v += __shfl_down(v, off);
        if (tid == 0) s_inv = 1.0f / v;
    }
    __syncthreads();

    // ---- Gm[i][j] = 0.5*(r_i r_j / ||r||^2 + 1) ----
    if (tid < NN * NN) {
        int i = tid / NN, j = tid % NN;
        gm[i][j] = 0.5f * (r[i] * r[j] * s_inv + 1.0f);
    }
    __syncthreads();

    // ---- conv1 (8,2,4,4), pad 1: (2,30,30) -> (8,29,29); channel 1 is
    //      constant 0.5 inside, 0 in the padding ring; LeakyReLU(0.2) ----
    for (int o = tid; o < 8 * 29 * 29; o += (int)blockDim.x) {
        int oc  = o / (29 * 29);
        int rem = o % (29 * 29);
        int oy  = rem / 29, ox = rem % 29;
        float acc = s_c1b[oc];
        #pragma unroll
        for (int ky = 0; ky < 4; ++ky) {
            int iy = oy + ky - 1;
            if (iy < 0 || iy >= NN) continue;
            #pragma unroll
            for (int kx = 0; kx < 4; ++kx) {
                int ix = ox + kx - 1;
                if (ix < 0 || ix >= NN) continue;
                float w0 = s_c1w[((oc * 2 + 0) * 4 + ky) * 4 + kx];
                float w1 = s_c1w[((oc * 2 + 1) * 4 + ky) * 4 + kx];
                acc += gm[iy][ix] * w0 + 0.5f * w1;
            }
        }
        c1[oc][oy][ox] = acc >= 0.f ? acc : 0.2f * acc;
    }
    __syncthreads();

    // ---- maxpool 8x8 stride 8 VALID: (8,29,29) -> (8,3,3) ----
    if (tid < 8 * 3 * 3) {
        int oc = tid / 9, py = (tid % 9) / 3, px = tid % 3;
        float m = -INFINITY;
        for (int dy = 0; dy < 8; ++dy)
            for (int dx = 0; dx < 8; ++dx) {
                float v = c1[oc][py * 8 + dy][px * 8 + dx];
                m = v > m ? v : m;
            }
        p1[oc][py][px] = m;
    }
    __syncthreads();

    // ---- conv2 (16,8,2,2), pad 1: (8,3,3) -> (16,4,4), LeakyReLU(0.2) ----
    if (tid < 16 * 4 * 4) {
        int oc = tid / 16, rem = tid % 16;
        int oy = rem / 4, ox = rem % 4;
        float acc = s_c2b[oc];
        for (int ic = 0; ic < 8; ++ic) {
            #pragma unroll
            for (int ky = 0; ky < 2; ++ky) {
                int iy = oy + ky - 1;
                if (iy < 0 || iy >= 3) continue;
                #pragma unroll
                for (int kx = 0; kx < 2; ++kx) {
                    int ix = ox + kx - 1;
                    if (ix < 0 || ix >= 3) continue;
                    acc += p1[ic][iy][ix] * s_c2w[((oc * 8 + ic) * 2 + ky) * 2 + kx];
                }
            }
        }
        c2o[oc][oy][ox] = acc >= 0.f ? acc : 0.2f * acc;
    }
    __syncthreads();

    // ---- maxpool 4x4: (16,4,4) -> (16,) ----
    if (tid < 16) {
        float m = -INFINITY;
        for (int dy = 0; dy < 4; ++dy)
            for (int dx = 0; dx < 4; ++dx) {
                float v = c2o[tid][dy][dx];
                m = v > m ? v : m;
            }
        hvec[tid] = m;
    }
    __syncthreads();

    // ---- final linear: out[k] = sum_c h[c]*out_w[k,c] + out_b[k] ----
    if (tid < 2) {
        float acc = s_ob[tid];
        #pragma unroll
        for (int c = 0; c < 16; ++c) acc += hvec[c] * s_ow[tid * 16 + c];
        out[tid] = acc;
    }
}

extern "C" void kernel_launch(void* const* d_in, const int* in_sizes, int n_in,
                              void* d_out, int out_size, void* d_ws, size_t ws_size,
                              hipStream_t stream) {
    // d_in order: 0=x(unused), 1=W, 2=conv1_w, 3=conv1_b, 4=conv2_w,
    // 5=conv2_b, 6=out_w, 7=out_b, 8=col(unused — cancels in trace norm)
    const float* W   = (const float*)d_in[1];
    const float* c1w = (const float*)d_in[2];
    const float* c1b = (const float*)d_in[3];
    const float* c2w = (const float*)d_in[4];
    const float* c2b = (const float*)d_in[5];
    const float* ow  = (const float*)d_in[6];
    const float* ob  = (const float*)d_in[7];
    float* out = (float*)d_out;

    cnn2_fused<<<1, 1024, 0, stream>>>(W, c1w, c1b, c2w, c2b, ow, ob, out);
}

// Round 3
// 9.960 us; speedup vs baseline: 2.0587x; 1.6972x over previous
//
#include <hip/hip_runtime.h>

// CNN2: reference collapses because Y = W @ ones(30,T) is rank-1 (every column
// == rowsum(W) = r). Per-lag trace normalization cancels the lag-dependent
// overlap count, so S_mean is lag-independent:
//   Sm = r r^T / ||r||^2,  Sv = 0  (fp noise ~1e-17)
//   Gm = 0.5*(Sm+1), Gv = 0.5 (constant channel), pad = 0
// R2: never materialize Gm — conv1 valid-tap contribution is
//   (0.5*s_inv*r_iy*r_ix + 0.5)*w0 + 0.5*w1
// fuse pool1 into conv1 (only the 24x24 region feeds the pool; 8 lanes per
// window + shfl max); fuse rowsum+ssq (one wave, register shuffles); fuse
// pool2+linear (one wave, float4 + shuffles). 4 barriers total, 8 KB LDS.

#define NN 30

__global__ __launch_bounds__(576) void cnn2_fused(
    const float4* __restrict__ W4,
    const float4* __restrict__ c1w4, const float* __restrict__ c1b,
    const float4* __restrict__ c2w4, const float* __restrict__ c2b,
    const float4* __restrict__ ow4,  const float* __restrict__ ob,
    float* __restrict__ out)
{
    __shared__ __align__(16) float w[900];      // staged W
    __shared__ __align__(16) float s_c1w[256];
    __shared__ __align__(16) float s_c2w[512];
    __shared__ __align__(16) float s_ow[32];
    __shared__ float s_c1b[8], s_c2b[16], s_ob[2];
    __shared__ float r[NN];
    __shared__ float s_hsinv;                   // 0.5 / ||r||^2
    __shared__ float p1[72];                    // pool1: oc*9 + py*3 + px
    __shared__ __align__(16) float c2o[256];    // conv2 out: oc*16 + oy*4 + ox

    const int tid = threadIdx.x;

    // ---- Phase A: every global load, vectorized, one parallel burst ----
    if (tid < 225)      ((float4*)w)[tid]           = W4[tid];
    else if (tid < 289) ((float4*)s_c1w)[tid - 225] = c1w4[tid - 225];
    else if (tid < 417) ((float4*)s_c2w)[tid - 289] = c2w4[tid - 289];
    else if (tid < 425) ((float4*)s_ow)[tid - 417]  = ow4[tid - 417];
    else if (tid < 433) s_c1b[tid - 425] = c1b[tid - 425];
    else if (tid < 449) s_c2b[tid - 433] = c2b[tid - 433];
    else if (tid < 451) s_ob[tid - 449]  = ob[tid - 449];
    __syncthreads();                                            // b1

    // ---- Phase B (wave 0): rowsum + ssq, no intermediate barrier ----
    if (tid < 64) {
        float s = 0.f;
        if (tid < NN) {
            #pragma unroll
            for (int j = 0; j < NN; ++j) s += w[tid * NN + j];
            r[tid] = s;
        }
        float v = s * s;                    // lanes >= 30 contribute 0
        #pragma unroll
        for (int m = 32; m; m >>= 1) v += __shfl_xor(v, m);
        if (tid == 0) s_hsinv = 0.5f / v;
    }
    __syncthreads();                                            // b2

    // ---- Phase C: conv1 + leaky + pool1, fused. 8 lanes per pool window.
    // Window (oc,py,px); lane handles output row oy = py*8 + (tid&7),
    // 8 outputs ox = px*8 .. px*8+7. Only iy/ix >= 0 can clip (region 0..23,
    // taps reach -1..25 < 30).
    {
        const int wdw = tid >> 3;           // 0..71
        const int row = tid & 7;
        const int oc  = wdw / 9;
        const int rm  = wdw % 9;
        const int py  = rm / 3, px = rm % 3;
        const int oy  = py * 8 + row;
        const float hsinv = s_hsinv;

        float ry[4];
        #pragma unroll
        for (int ky = 0; ky < 4; ++ky) {
            int iy = oy + ky - 1;
            ry[ky] = (iy >= 0) ? r[iy] : 0.f;
        }
        float rv[11];
        #pragma unroll
        for (int j = 0; j < 11; ++j) {
            int ix = px * 8 - 1 + j;
            rv[j] = (ix >= 0) ? r[ix] : 0.f;
        }
        // weights folded with ry (invalid rows auto-zero); w-sum terms masked
        float wry[16];
        float sw_full = 0.f, sw_col0 = 0.f;
        #pragma unroll
        for (int ky = 0; ky < 4; ++ky) {
            const bool vld = (oy + ky - 1) >= 0;
            #pragma unroll
            for (int kx = 0; kx < 4; ++kx) {
                float w0 = s_c1w[(oc * 2 + 0) * 16 + ky * 4 + kx];
                float w1 = s_c1w[(oc * 2 + 1) * 16 + ky * 4 + kx];
                wry[ky * 4 + kx] = ry[ky] * w0;
                if (vld) {
                    float sw = w0 + w1;
                    sw_full += sw;
                    if (kx == 0) sw_col0 += sw;
                }
            }
        }
        const float bias = s_c1b[oc];
        float m = -INFINITY;
        #pragma unroll
        for (int q = 0; q < 8; ++q) {
            float acc = 0.f;
            #pragma unroll
            for (int ky = 0; ky < 4; ++ky)
                #pragma unroll
                for (int kx = 0; kx < 4; ++kx)
                    acc += rv[q + kx] * wry[ky * 4 + kx];
            float aw  = (px == 0 && q == 0) ? (sw_full - sw_col0) : sw_full;
            float val = bias + hsinv * acc + 0.5f * aw;
            val = val >= 0.f ? val : 0.2f * val;
            m = fmaxf(m, val);
        }
        m = fmaxf(m, __shfl_xor(m, 1));
        m = fmaxf(m, __shfl_xor(m, 2));
        m = fmaxf(m, __shfl_xor(m, 4));
        if (row == 0) p1[wdw] = m;
    }
    __syncthreads();                                            // b3

    // ---- Phase D: conv2 (16,8,2,2), pad 1: (8,3,3)->(16,4,4), leaky ----
    if (tid < 256) {
        const int oc = tid >> 4, rem = tid & 15;
        const int oy = rem >> 2, ox = rem & 3;
        float acc = s_c2b[oc];
        #pragma unroll
        for (int ky = 0; ky < 2; ++ky) {
            const int iy = oy + ky - 1;
            if (iy < 0 || iy > 2) continue;
            #pragma unroll
            for (int kx = 0; kx < 2; ++kx) {
                const int ix = ox + kx - 1;
                if (ix < 0 || ix > 2) continue;
                #pragma unroll
                for (int ic = 0; ic < 8; ++ic)
                    acc += p1[ic * 9 + iy * 3 + ix] *
                           s_c2w[((oc * 8 + ic) * 2 + ky) * 2 + kx];
            }
        }
        acc = acc >= 0.f ? acc : 0.2f * acc;
        c2o[oc * 16 + oy * 4 + ox] = acc;
    }
    __syncthreads();                                            // b4

    // ---- Phase E (wave 0): pool2 + linear, shuffles only ----
    if (tid < 64) {
        const int c = tid >> 2, q = tid & 3;
        float4 v = ((const float4*)c2o)[c * 4 + q];
        float m = fmaxf(fmaxf(v.x, v.y), fmaxf(v.z, v.w));
        m = fmaxf(m, __shfl_xor(m, 1));
        m = fmaxf(m, __shfl_xor(m, 2));          // h[c] in lanes 4c..4c+3
        float h = __shfl(m, (tid & 15) << 2);    // gather h[tid&15]
        float part = (tid < 32) ? h * s_ow[tid] : 0.f;
        part += __shfl_xor(part, 8);
        part += __shfl_xor(part, 4);
        part += __shfl_xor(part, 2);
        part += __shfl_xor(part, 1);
        if (tid == 0)  out[0] = part + s_ob[0];
        if (tid == 16) out[1] = part + s_ob[1];
    }
}

extern "C" void kernel_launch(void* const* d_in, const int* in_sizes, int n_in,
                              void* d_out, int out_size, void* d_ws, size_t ws_size,
                              hipStream_t stream) {
    // d_in order: 0=x(unused), 1=W, 2=conv1_w, 3=conv1_b, 4=conv2_w,
    // 5=conv2_b, 6=out_w, 7=out_b, 8=col(unused — cancels in trace norm)
    const float4* W4   = (const float4*)d_in[1];
    const float4* c1w4 = (const float4*)d_in[2];
    const float*  c1b  = (const float*)d_in[3];
    const float4* c2w4 = (const float4*)d_in[4];
    const float*  c2b  = (const float*)d_in[5];
    const float4* ow4  = (const float4*)d_in[6];
    const float*  ob   = (const float*)d_in[7];
    float* out = (float*)d_out;

    cnn2_fused<<<1, 576, 0, stream>>>(W4, c1w4, c1b, c2w4, c2b, ow4, ob, out);
}